// Round 2
// baseline (107.790 us; speedup 1.0000x reference)
//
#include <hip/hip_runtime.h>

#define N_BLOCKS 2048
#define N_THREADS 256

// Fused: per-block partial sum of (z1+z2+2.6)^2, last-finishing block does the
// final deterministic double-precision reduction and writes the scalar loss.
__global__ void __launch_bounds__(N_THREADS)
fused_loss_kernel(const float4* __restrict__ z1,
                  const float4* __restrict__ z2,
                  float* __restrict__ partials,
                  unsigned int* __restrict__ counter,
                  float* __restrict__ out,
                  int n4, double inv_n) {
    const int tid = blockIdx.x * blockDim.x + threadIdx.x;
    const int stride = gridDim.x * blockDim.x;

    float acc = 0.0f;
    int i = tid;
    // Unroll-by-4: 8 coalesced float4 loads (128 B) in flight per thread.
    for (; i + 3 * stride < n4; i += 4 * stride) {
        float4 a0 = z1[i];
        float4 a1 = z1[i + stride];
        float4 a2 = z1[i + 2 * stride];
        float4 a3 = z1[i + 3 * stride];
        float4 b0 = z2[i];
        float4 b1 = z2[i + stride];
        float4 b2 = z2[i + 2 * stride];
        float4 b3 = z2[i + 3 * stride];
        float t;
        t = a0.x + b0.x + 2.6f; acc = fmaf(t, t, acc);
        t = a0.y + b0.y + 2.6f; acc = fmaf(t, t, acc);
        t = a0.z + b0.z + 2.6f; acc = fmaf(t, t, acc);
        t = a0.w + b0.w + 2.6f; acc = fmaf(t, t, acc);
        t = a1.x + b1.x + 2.6f; acc = fmaf(t, t, acc);
        t = a1.y + b1.y + 2.6f; acc = fmaf(t, t, acc);
        t = a1.z + b1.z + 2.6f; acc = fmaf(t, t, acc);
        t = a1.w + b1.w + 2.6f; acc = fmaf(t, t, acc);
        t = a2.x + b2.x + 2.6f; acc = fmaf(t, t, acc);
        t = a2.y + b2.y + 2.6f; acc = fmaf(t, t, acc);
        t = a2.z + b2.z + 2.6f; acc = fmaf(t, t, acc);
        t = a2.w + b2.w + 2.6f; acc = fmaf(t, t, acc);
        t = a3.x + b3.x + 2.6f; acc = fmaf(t, t, acc);
        t = a3.y + b3.y + 2.6f; acc = fmaf(t, t, acc);
        t = a3.z + b3.z + 2.6f; acc = fmaf(t, t, acc);
        t = a3.w + b3.w + 2.6f; acc = fmaf(t, t, acc);
    }
    for (; i < n4; i += stride) {
        float4 a = z1[i];
        float4 b = z2[i];
        float t;
        t = a.x + b.x + 2.6f; acc = fmaf(t, t, acc);
        t = a.y + b.y + 2.6f; acc = fmaf(t, t, acc);
        t = a.z + b.z + 2.6f; acc = fmaf(t, t, acc);
        t = a.w + b.w + 2.6f; acc = fmaf(t, t, acc);
    }

    // wave-64 reduce
    #pragma unroll
    for (int off = 32; off > 0; off >>= 1)
        acc += __shfl_down(acc, off, 64);

    __shared__ float wave_sums[N_THREADS / 64];
    __shared__ int is_last;
    const int lane = threadIdx.x & 63;
    const int wave = threadIdx.x >> 6;
    if (lane == 0) wave_sums[wave] = acc;
    __syncthreads();

    if (threadIdx.x == 0) {
        float s = wave_sums[0] + wave_sums[1] + wave_sums[2] + wave_sums[3];
        partials[blockIdx.x] = s;
        __threadfence();  // make partial visible device-wide before ticket
        unsigned int old = atomicAdd(counter, 1u);
        // Works from ANY starting counter value (incl. 0xAAAAAAAA poison):
        // exactly one of gridDim consecutive tickets satisfies this.
        is_last = (((old + 1u) % (unsigned)gridDim.x) == 0u) ? 1 : 0;
    }
    __syncthreads();

    if (is_last) {
        __threadfence();
        double d = 0.0;
        // Fixed index order -> bitwise-deterministic result each call.
        for (int p = threadIdx.x; p < N_BLOCKS; p += N_THREADS)
            d += (double)__hip_atomic_load(&partials[p], __ATOMIC_RELAXED,
                                           __HIP_MEMORY_SCOPE_AGENT);
        #pragma unroll
        for (int off = 32; off > 0; off >>= 1)
            d += __shfl_down(d, off, 64);
        __shared__ double dsum[N_THREADS / 64];
        if (lane == 0) dsum[wave] = d;
        __syncthreads();
        if (threadIdx.x == 0) {
            double s = dsum[0] + dsum[1] + dsum[2] + dsum[3];
            // mean(log_likes) = -0.5 * sum(t^2) / N - 0.5*log(2*pi)
            out[0] = (float)(-0.5 * s * inv_n - 0.91893853320467274178);
        }
    }
}

extern "C" void kernel_launch(void* const* d_in, const int* in_sizes, int n_in,
                              void* d_out, int out_size, void* d_ws, size_t ws_size,
                              hipStream_t stream) {
    const float4* z1 = (const float4*)d_in[0];
    const float4* z2 = (const float4*)d_in[1];
    float* out = (float*)d_out;
    float* partials = (float*)d_ws;                       // 2048 floats
    unsigned int* counter = (unsigned int*)((char*)d_ws + N_BLOCKS * sizeof(float));

    int n = in_sizes[0];   // 33554432, divisible by 4
    int n4 = n / 4;

    fused_loss_kernel<<<N_BLOCKS, N_THREADS, 0, stream>>>(
        z1, z2, partials, counter, out, n4, 1.0 / (double)n);
}

// Round 3
// 47.616 us; speedup vs baseline: 2.2637x; 2.2637x over previous
//
#include <hip/hip_runtime.h>

#define N_BLOCKS 2048
#define N_THREADS 256

// Kernel 1: per-block partial sum of (z1+z2+2.6)^2 with 1-deep register
// prefetch. Grid-stride over float4; one float partial per block.
__global__ void __launch_bounds__(N_THREADS)
partial_sumsq_kernel(const float4* __restrict__ z1,
                     const float4* __restrict__ z2,
                     float* __restrict__ partials,
                     int n4) {
    const int tid = blockIdx.x * blockDim.x + threadIdx.x;
    const int stride = gridDim.x * blockDim.x;

    float acc = 0.0f;
    int i = tid;
    if (i < n4) {
        float4 a = z1[i];
        float4 b = z2[i];
        for (int ni = i + stride; ni < n4; ni += stride) {
            // issue next-iteration loads before consuming current regs
            float4 an = z1[ni];
            float4 bn = z2[ni];
            float t;
            t = a.x + b.x + 2.6f; acc += t * t;
            t = a.y + b.y + 2.6f; acc += t * t;
            t = a.z + b.z + 2.6f; acc += t * t;
            t = a.w + b.w + 2.6f; acc += t * t;
            a = an; b = bn;
        }
        float t;
        t = a.x + b.x + 2.6f; acc += t * t;
        t = a.y + b.y + 2.6f; acc += t * t;
        t = a.z + b.z + 2.6f; acc += t * t;
        t = a.w + b.w + 2.6f; acc += t * t;
    }

    // wave-64 reduce
    #pragma unroll
    for (int off = 32; off > 0; off >>= 1)
        acc += __shfl_down(acc, off, 64);

    __shared__ float wave_sums[N_THREADS / 64];
    const int lane = threadIdx.x & 63;
    const int wave = threadIdx.x >> 6;
    if (lane == 0) wave_sums[wave] = acc;
    __syncthreads();

    if (threadIdx.x == 0) {
        float s = wave_sums[0] + wave_sums[1] + wave_sums[2] + wave_sums[3];
        partials[blockIdx.x] = s;
    }
}

// Kernel 2: deterministic double-precision reduce of the 2048 partials.
__global__ void __launch_bounds__(N_THREADS)
final_reduce_kernel(const float4* __restrict__ partials4,
                    int nparts4,
                    float* __restrict__ out,
                    double inv_n) {
    double acc = 0.0;
    for (int i = threadIdx.x; i < nparts4; i += blockDim.x) {
        float4 p = partials4[i];
        acc += (double)p.x + (double)p.y + (double)p.z + (double)p.w;
    }

    #pragma unroll
    for (int off = 32; off > 0; off >>= 1)
        acc += __shfl_down(acc, off, 64);

    __shared__ double wave_sums[N_THREADS / 64];
    const int lane = threadIdx.x & 63;
    const int wave = threadIdx.x >> 6;
    if (lane == 0) wave_sums[wave] = acc;
    __syncthreads();

    if (threadIdx.x == 0) {
        double s = wave_sums[0] + wave_sums[1] + wave_sums[2] + wave_sums[3];
        // mean(log_likes) = -0.5 * sum(t^2) / N - 0.5*log(2*pi)
        out[0] = (float)(-0.5 * s * inv_n - 0.91893853320467274178);
    }
}

extern "C" void kernel_launch(void* const* d_in, const int* in_sizes, int n_in,
                              void* d_out, int out_size, void* d_ws, size_t ws_size,
                              hipStream_t stream) {
    const float4* z1 = (const float4*)d_in[0];
    const float4* z2 = (const float4*)d_in[1];
    float* out = (float*)d_out;
    float* partials = (float*)d_ws;  // 2048 floats = 8 KB scratch

    int n = in_sizes[0];   // 33554432, divisible by 4
    int n4 = n / 4;

    partial_sumsq_kernel<<<N_BLOCKS, N_THREADS, 0, stream>>>(z1, z2, partials, n4);
    final_reduce_kernel<<<1, N_THREADS, 0, stream>>>((const float4*)partials,
                                                     N_BLOCKS / 4, out,
                                                     1.0 / (double)n);
}